// Round 12
// baseline (1132.196 us; speedup 1.0000x reference)
//
#include <hip/hip_runtime.h>
#include <hip/hip_bf16.h>
#include <stdint.h>

#define USER_DIM 3706
#define ITEM_DIM 6040
#define LATENT   512
#define BATCH    8192
#define XCOLS    (USER_DIM + ITEM_DIM)   // 9746
#define KPAD_U   3712                     // 116*32: full=116 steps, halves=58
#define KPAD_I   6144                     // 192*32: halves=96, thirds=64

typedef float f32x4 __attribute__((ext_vector_type(4)));
typedef short bf16x8 __attribute__((ext_vector_type(8)));

#define VMCNT(n) asm volatile("s_waitcnt vmcnt(" #n ")" ::: "memory")
#define LGKM0    asm volatile("s_waitcnt lgkmcnt(0)" ::: "memory")

static __device__ __forceinline__ unsigned short f2bf(float f) {
    union { float f; unsigned int u; } v; v.f = f;
    unsigned int u = v.u;
    u += 0x7fffu + ((u >> 16) & 1u);   // RNE (finite inputs)
    return (unsigned short)(u >> 16);
}
static __device__ __forceinline__ float bf2f(unsigned int b) {
    union { unsigned int u; float f; } v; v.u = b << 16; return v.f;
}
static __device__ __forceinline__ void gload16(const void* g, void* l) {
    __builtin_amdgcn_global_load_lds(
        (const __attribute__((address_space(1))) void*)g,
        (__attribute__((address_space(3))) void*)l, 16, 0, 0);
}
static __device__ __forceinline__ void BARRIER() {
    __builtin_amdgcn_sched_barrier(0);
    __builtin_amdgcn_s_barrier();
    __builtin_amdgcn_sched_barrier(0);
}

// ---- Kernel 1: weight fp32 -> bf16, zero-padded K ----
__global__ void convert_w(const float* __restrict__ W, unsigned short* __restrict__ Wb,
                          int K, int Kpad) {
    int c = blockIdx.x * blockDim.x + threadIdx.x;
    int r = blockIdx.y;
    if (c >= Kpad) return;
    unsigned short o = 0;
    if (c < K) o = f2bf(W[(size_t)r * K + c]);
    Wb[(size_t)r * Kpad + c] = o;
}

// ---- Kernel 2: round-6 body. 128x128 tile, BK=32, 4 waves, 32 KB LDS.
// A reg-staged 2-deep (rotation: iter t AWRITEs the set loaded at t-1, reloads
// the other), write-side fp32->bf16 cvt. B via global_load_lds. Counted vmcnt
// mid-loop (never 0). FIXED TAIL (r11 bug): the last pair's A-write + B-drain
// now happen explicitly after the loop. All outputs raw bf16 partials.
// mode5=1: 1280 blocks (5/CU) = user 2 K-halves (58) + item 3 K-thirds (64).
// mode5=0: 768 blocks (3/CU)  = user full (116)    + item 2 K-halves (96).
__global__ __launch_bounds__(256, 5) void gemm_fused(
    const float* __restrict__ X,
    const unsigned short* __restrict__ WuB,
    const unsigned short* __restrict__ WiB,
    unsigned short* __restrict__ U0, unsigned short* __restrict__ U1,
    unsigned short* __restrict__ P0, unsigned short* __restrict__ P1,
    unsigned short* __restrict__ P2,
    int mode5)
{
    __shared__ unsigned short sA2[2][64 * 64];   // 2 x 8 KB bf16
    __shared__ unsigned short sB2[2][64 * 64];   // 2 x 8 KB bf16

    const int tid  = threadIdx.x;
    const int lane = tid & 63;
    const int wid  = tid >> 6;
    const int wm   = wid >> 1;
    const int wn   = wid & 1;

    const int bid = blockIdx.x;
    int mb, nb, k0s, nt, xoff, Kpad;
    const unsigned short* WB;
    unsigned short* dst;
    if (mode5) {
        // 1280 = 8 XCDs x 160; 5-group = {2 user halves, 3 item thirds} of one (mb,nb)
        const int swz = (bid & 7) * 160 + (bid >> 3);
        const int g5  = swz / 5;            // 0..255
        const int r   = swz - g5 * 5;       // 0..4
        mb = g5 >> 2; nb = g5 & 3;
        if (r < 2) { k0s = r * 58;       nt = 58; xoff = 0;        Kpad = KPAD_U; WB = WuB;
                     dst = r ? U1 : U0; }
        else       { const int kth = r - 2;
                     k0s = kth * 64;     nt = 64; xoff = USER_DIM; Kpad = KPAD_I; WB = WiB;
                     dst = (kth == 0) ? P0 : (kth == 1) ? P1 : P2; }
    } else {
        // 768 = 8 x 96 (round-6 mapping)
        const int swz = (bid & 7) * 96 + (bid >> 3);
        const int g4  = swz >> 2;
        nb = swz & 3;
        if (g4 % 3 == 0) { mb = g4 / 3; k0s = 0; nt = 116; xoff = 0;
                           Kpad = KPAD_U; WB = WuB; dst = U0; }
        else             { const int q = g4 - (g4 / 3 + 1);
                           mb = q >> 1; const int kh = q & 1;
                           k0s = kh * 96; nt = 96; xoff = USER_DIM;
                           Kpad = KPAD_I; WB = WiB; dst = kh ? P1 : P0; }
    }

    // ---- staging lane geometry (LDS[seg][c8] holds global
    //      (row = seg*2 + ((c8^(seg&7))>>2), kchunk = (c8^(seg&7))&3)) ----
    const int l8  = lane >> 3;                 // seg within group
    const int c8w = lane & 7;                  // LDS chunk this lane fills
    const int s8  = c8w ^ l8;                  // source-side swizzled chunk
    const int spr = s8 >> 2;                   // source row parity
    const int skc = (s8 & 3) * 8;              // source k-col (elements)

    const int asg0 = wid * 16 + l8;            // A op0 seg
    const float* aptr0 = X + (size_t)(mb * 128 + asg0 * 2 + spr) * XCOLS + xoff;
    const float* aptr1 = aptr0 + (size_t)16 * XCOLS;   // op1 seg = asg0 + 8

    auto ALOAD = [&](float4 (&R)[2], float4 (&S)[2], int tk) {
        int kc = tk * 32 + skc;
        if (xoff + kc + 8 > XCOLS) kc = XCOLS - xoff - 8;  // tail: junk x 0-B
        R[0] = *(const float4*)(aptr0 + kc);
        R[1] = *(const float4*)(aptr0 + kc + 4);
        S[0] = *(const float4*)(aptr1 + kc);
        S[1] = *(const float4*)(aptr1 + kc + 4);
    };
    auto AWRITE = [&](const float4 (&R)[2], const float4 (&S)[2], int buf) {
        unsigned short* sA = sA2[buf];
        uint4 w0, w1;
        w0.x = (unsigned)f2bf(R[0].x) | ((unsigned)f2bf(R[0].y) << 16);
        w0.y = (unsigned)f2bf(R[0].z) | ((unsigned)f2bf(R[0].w) << 16);
        w0.z = (unsigned)f2bf(R[1].x) | ((unsigned)f2bf(R[1].y) << 16);
        w0.w = (unsigned)f2bf(R[1].z) | ((unsigned)f2bf(R[1].w) << 16);
        w1.x = (unsigned)f2bf(S[0].x) | ((unsigned)f2bf(S[0].y) << 16);
        w1.y = (unsigned)f2bf(S[0].z) | ((unsigned)f2bf(S[0].w) << 16);
        w1.z = (unsigned)f2bf(S[1].x) | ((unsigned)f2bf(S[1].y) << 16);
        w1.w = (unsigned)f2bf(S[1].z) | ((unsigned)f2bf(S[1].w) << 16);
        *(uint4*)(sA + asg0 * 64 + c8w * 8) = w0;
        *(uint4*)(sA + (asg0 + 8) * 64 + c8w * 8) = w1;
    };
    auto ISSUE_B = [&](int tk, int buf) {
        const int kb = tk * 32;
        unsigned short* sB = sB2[buf];
        #pragma unroll
        for (int j = 0; j < 2; ++j) {
            const int i  = wid * 2 + j;                // 0..7
            const int rt = (i * 8 + l8) * 2 + spr;     // tile row
            const unsigned short* s =
                WB + (size_t)(nb * 128 + rt) * Kpad + kb + skc;
            gload16(s, sB + i * 512);                  // linear 1KB dest
        }
    };

    // ---- fragment read geometry (0-conflict) ----
    const int fr  = lane & 15;
    const int g   = lane >> 4;
    const int lro = (fr >> 1) * 64 + ((((fr & 1) * 4) + g) ^ (fr >> 1)) * 8;
    const int aro = wm * 2048 + lro;           // + mi*512
    const int bro = wn * 2048 + lro;           // + ni*512

    f32x4 acc[4][4];
    #pragma unroll
    for (int i = 0; i < 4; ++i)
        #pragma unroll
        for (int j = 0; j < 4; ++j) acc[i][j] = (f32x4)0.0f;

    auto COMPUTE = [&](int buf) {
        const unsigned short* sA = sA2[buf];
        const unsigned short* sB = sB2[buf];
        bf16x8 af[4], bfr[4];
        #pragma unroll
        for (int mi = 0; mi < 4; ++mi)
            af[mi] = *(const bf16x8*)(sA + aro + mi * 512);
        #pragma unroll
        for (int ni = 0; ni < 4; ++ni)
            bfr[ni] = *(const bf16x8*)(sB + bro + ni * 512);
        __builtin_amdgcn_s_setprio(1);
        #pragma unroll
        for (int mi = 0; mi < 4; ++mi)
            #pragma unroll
            for (int ni = 0; ni < 4; ++ni)
                acc[mi][ni] = __builtin_amdgcn_mfma_f32_16x16x32_bf16(
                    af[mi], bfr[ni], acc[mi][ni], 0, 0, 0);
        __builtin_amdgcn_s_setprio(0);
    };

    float4 S0a[2], S0b[2], S1a[2], S1b[2];     // 2-deep A reg sets (named)

    // ---- prologue ----
    ALOAD(S0a, S0b, k0s);           // S0 = A(0)        [4 vm]
    ISSUE_B(k0s, 0);                // B(0) -> buf0     [2 vm]
    AWRITE(S0a, S0b, 0);            // stage A(0) (auto-waits its 4 loads)
    ALOAD(S1a, S1b, k0s + 1);       // S1 = A(1)
    LGKM0;
    VMCNT(4);                       // B(0) landed (A(1) stays in flight)
    BARRIER();                      // tile 0 ready
    ISSUE_B(k0s + 1, 1);            // B(1) in flight

    // Invariant entering even step t: buf0 = tile t ready; S1 = A(t+1);
    // outstanding = [4xA(t+1)... wait set below], B(t+1) in flight -> buf1.
    for (int t = 0; t < nt - 2; t += 2) {
        // even: compute tile t; stage A(t+1)->buf1; load A(t+2)->S0
        COMPUTE(0);
        AWRITE(S1a, S1b, 1);        // auto-retires A(t+1) loads
        ALOAD(S0a, S0b, k0s + t + 2);
        LGKM0;
        BARRIER();                  // buf0 reads done everywhere
        ISSUE_B(k0s + t + 2, 0);    // B(t+2) -> buf0
        VMCNT(6);                   // retires B(t+1)
        BARRIER();                  // publish tile t+1 (buf1)
        // odd: compute tile t+1; stage A(t+2)->buf0; load A(t+3)->S1
        COMPUTE(1);
        AWRITE(S0a, S0b, 0);        // auto-retires A(t+2) loads
        ALOAD(S1a, S1b, k0s + t + 3);   // at t=nt-4 this is A(nt-1): valid
        LGKM0;
        BARRIER();                  // buf1 reads done everywhere
        ISSUE_B(k0s + t + 3, 1);    // B(t+3) -> buf1 (at t=nt-4: B(nt-1))
        VMCNT(6);                   // retires B(t+2)
        BARRIER();                  // publish tile t+2 (buf0)
    }
    // ---- tail (r11 fix): buf0 = tile nt-2 ready; S1 = A(nt-1) in regs;
    //      B(nt-1) in flight -> buf1, never yet waited.
    COMPUTE(0);                     // tile nt-2
    AWRITE(S1a, S1b, 1);            // A(nt-1) -> buf1 (auto-retires its loads)
    LGKM0;
    BARRIER();                      // all A(nt-1) writes visible
    VMCNT(0);                       // drain B(nt-1) DMA
    BARRIER();
    COMPUTE(1);                     // tile nt-1

    // ---- epilogue: raw partial store (bias+relu in rowdot) ----
    const int cb = nb * 128 + wn * 64;
    const int rb = mb * 128 + wm * 64 + (lane >> 4) * 4;
    #pragma unroll
    for (int ni = 0; ni < 4; ++ni) {
        const int col = cb + ni * 16 + fr;
        #pragma unroll
        for (int mi = 0; mi < 4; ++mi) {
            f32x4 v = acc[mi][ni];
            #pragma unroll
            for (int r = 0; r < 4; ++r) {
                const int row = rb + mi * 16 + r;
                dst[(size_t)row * LATENT + col] = f2bf(v[r]);
            }
        }
    }
}

// ---- Kernel 3: out[b] = relu(ΣU+bu) . relu(ΣP+bi) ----
__global__ void rowdot(const unsigned short* __restrict__ U0,
                       const unsigned short* __restrict__ U1,
                       const unsigned short* __restrict__ P0,
                       const unsigned short* __restrict__ P1,
                       const unsigned short* __restrict__ P2,
                       const float* __restrict__ bu,
                       const float* __restrict__ bi,
                       float* __restrict__ out,
                       int mode5) {
    const int lane = threadIdx.x & 63;
    const int w    = threadIdx.x >> 6;
    const int row  = blockIdx.x * 4 + w;
    const size_t base = (size_t)row * LATENT + lane * 8;
    const uint4 u0 = *(const uint4*)(U0 + base);
    const uint4 p0 = *(const uint4*)(P0 + base);
    const uint4 p1 = *(const uint4*)(P1 + base);
    uint4 u1 = make_uint4(0, 0, 0, 0), p2 = make_uint4(0, 0, 0, 0);
    if (mode5) { u1 = *(const uint4*)(U1 + base); p2 = *(const uint4*)(P2 + base); }
    const float4 bu0 = *(const float4*)(bu + lane * 8);
    const float4 bu1 = *(const float4*)(bu + lane * 8 + 4);
    const float4 bi0 = *(const float4*)(bi + lane * 8);
    const float4 bi1 = *(const float4*)(bi + lane * 8 + 4);
    const float bbu[8] = {bu0.x, bu0.y, bu0.z, bu0.w, bu1.x, bu1.y, bu1.z, bu1.w};
    const float bbi[8] = {bi0.x, bi0.y, bi0.z, bi0.w, bi1.x, bi1.y, bi1.z, bi1.w};
    const unsigned int* a0 = (const unsigned int*)&u0;
    const unsigned int* a1 = (const unsigned int*)&u1;
    const unsigned int* q0 = (const unsigned int*)&p0;
    const unsigned int* q1 = (const unsigned int*)&p1;
    const unsigned int* q2 = (const unsigned int*)&p2;
    float acc = 0.0f;
    #pragma unroll
    for (int q = 0; q < 4; ++q) {
        float ulo = bf2f(a0[q] & 0xffffu), uhi = bf2f(a0[q] >> 16);
        float ilo = bf2f(q0[q] & 0xffffu) + bf2f(q1[q] & 0xffffu);
        float ihi = bf2f(q0[q] >> 16)     + bf2f(q1[q] >> 16);
        if (mode5) {
            ulo += bf2f(a1[q] & 0xffffu); uhi += bf2f(a1[q] >> 16);
            ilo += bf2f(q2[q] & 0xffffu); ihi += bf2f(q2[q] >> 16);
        }
        ulo = fmaxf(ulo + bbu[2 * q], 0.0f);
        uhi = fmaxf(uhi + bbu[2 * q + 1], 0.0f);
        ilo = fmaxf(ilo + bbi[2 * q], 0.0f);
        ihi = fmaxf(ihi + bbi[2 * q + 1], 0.0f);
        acc += ulo * ilo + uhi * ihi;
    }
    #pragma unroll
    for (int off = 32; off >= 1; off >>= 1)
        acc += __shfl_xor(acc, off, 64);
    if (lane == 0) out[row] = acc;
}

extern "C" void kernel_launch(void* const* d_in, const int* in_sizes, int n_in,
                              void* d_out, int out_size, void* d_ws, size_t ws_size,
                              hipStream_t stream) {
    const float* x  = (const float*)d_in[0];
    const float* Wu = (const float*)d_in[1];
    const float* bu = (const float*)d_in[2];
    const float* Wi = (const float*)d_in[3];
    const float* bi = (const float*)d_in[4];
    float* out = (float*)d_out;

    // layout: mode-B footprint first, extra surfaces (U1, P2) at the end
    unsigned short* WuB = (unsigned short*)d_ws;                  // 512*3712 bf16
    unsigned short* WiB = WuB + (size_t)LATENT * KPAD_U;          // 512*6144 bf16
    unsigned short* U0  = WiB + (size_t)LATENT * KPAD_I;          // 8 MB
    unsigned short* P0  = U0  + (size_t)BATCH * LATENT;           // 8 MB
    unsigned short* P1  = P0  + (size_t)BATCH * LATENT;           // 8 MB
    unsigned short* U1  = P1  + (size_t)BATCH * LATENT;           // 8 MB (mode5)
    unsigned short* P2  = U1  + (size_t)BATCH * LATENT;           // 8 MB (mode5)

    const size_t need5 = ((size_t)LATENT * (KPAD_U + KPAD_I)
                        + (size_t)5 * BATCH * LATENT) * sizeof(unsigned short);
    const int mode5 = (ws_size >= need5) ? 1 : 0;

    convert_w<<<dim3((KPAD_U + 255) / 256, LATENT), 256, 0, stream>>>(Wu, WuB, USER_DIM, KPAD_U);
    convert_w<<<dim3((KPAD_I + 255) / 256, LATENT), 256, 0, stream>>>(Wi, WiB, ITEM_DIM, KPAD_I);

    gemm_fused<<<mode5 ? 1280 : 768, 256, 0, stream>>>(
        x, WuB, WiB, U0, U1, P0, P1, P2, mode5);

    rowdot<<<BATCH / 4, 256, 0, stream>>>(U0, U1, P0, P1, P2, bu, bi, out, mode5);
}

// Round 13
// 243.159 us; speedup vs baseline: 4.6562x; 4.6562x over previous
//
#include <hip/hip_runtime.h>
#include <hip/hip_bf16.h>
#include <stdint.h>

#define USER_DIM 3706
#define ITEM_DIM 6040
#define LATENT   512
#define BATCH    8192
#define XCOLS    (USER_DIM + ITEM_DIM)   // 9746
#define KPAD_U   3712                     // 116 * 32
#define KPAD_I   6144                     // 192 * 32 (two halves of 96 steps)

typedef float f32x4 __attribute__((ext_vector_type(4)));
typedef short bf16x8 __attribute__((ext_vector_type(8)));

#define VMCNT(n) asm volatile("s_waitcnt vmcnt(" #n ")" ::: "memory")
#define LGKM0    asm volatile("s_waitcnt lgkmcnt(0)" ::: "memory")

static __device__ __forceinline__ unsigned short f2bf(float f) {
    union { float f; unsigned int u; } v; v.f = f;
    unsigned int u = v.u;
    u += 0x7fffu + ((u >> 16) & 1u);   // RNE (finite inputs)
    return (unsigned short)(u >> 16);
}
static __device__ __forceinline__ float bf2f(unsigned int b) {
    union { unsigned int u; float f; } v; v.u = b << 16; return v.f;
}
static __device__ __forceinline__ void gload16(const void* g, void* l) {
    __builtin_amdgcn_global_load_lds(
        (const __attribute__((address_space(1))) void*)g,
        (__attribute__((address_space(3))) void*)l, 16, 0, 0);
}
static __device__ __forceinline__ void BARRIER() {
    __builtin_amdgcn_sched_barrier(0);
    __builtin_amdgcn_s_barrier();
    __builtin_amdgcn_sched_barrier(0);
}

// ---- Kernel 1: weight fp32 -> bf16, zero-padded K ----
__global__ void convert_w(const float* __restrict__ W, unsigned short* __restrict__ Wb,
                          int K, int Kpad) {
    int c = blockIdx.x * blockDim.x + threadIdx.x;
    int r = blockIdx.y;
    if (c >= Kpad) return;
    unsigned short o = 0;
    if (c < K) o = f2bf(W[(size_t)r * K + c]);
    Wb[(size_t)r * Kpad + c] = o;
}

// ---- Kernel 2: fused towers, 128x128 tile, BK=32, 4 waves, 48 KB LDS.
// ONE barrier per K-step: 3-deep LDS rings for A and B.  At step t:
//   read slot t%3;  A ds_write -> slot (t+1)%3;  B DMA -> slot (t+2)%3
// (all distinct mod 3; barrier-per-step keeps skew <= 1 -> race-free).
// A reg-staged single set (write-then-reload, r6-proven), write-side cvt.
// Steady vmcnt(6) retires exactly B(t+1); never drains mid-loop.
// Decomposition (r6-proven): per CU 1 user (116 steps) + 2 item halves (96).
__global__ __launch_bounds__(256, 3) void gemm_fused(
    const float* __restrict__ X,
    const unsigned short* __restrict__ WuB, const float* __restrict__ bu,
    const unsigned short* __restrict__ WiB,
    unsigned short* __restrict__ Uemb,
    unsigned short* __restrict__ P0, unsigned short* __restrict__ P1)
{
    __shared__ unsigned short sA3[3][64 * 64];   // 3 x 8 KB bf16 ring
    __shared__ unsigned short sB3[3][64 * 64];   // 3 x 8 KB bf16 ring

    const int tid  = threadIdx.x;
    const int lane = tid & 63;
    const int wid  = tid >> 6;
    const int wm   = wid >> 1;
    const int wn   = wid & 1;

    // XCD-chunked bijective swizzle over 768 blocks (= 8 * 96).
    const int bid = blockIdx.x;
    const int swz = (bid & 7) * 96 + (bid >> 3);
    const int g4  = swz >> 2;          // 0..191
    const int nb  = swz & 3;

    int mb, k0s, nt, xoff, Kpad;
    const unsigned short* WB;
    bool isUser; int kh = 0;
    if (g4 % 3 == 0) {
        isUser = true;  mb = g4 / 3;
        k0s = 0; nt = 116; xoff = 0; Kpad = KPAD_U; WB = WuB;
    } else {
        const int q = g4 - (g4 / 3 + 1);     // 0..127 bijective
        isUser = false; mb = q >> 1; kh = q & 1;
        k0s = kh * 96; nt = 96; xoff = USER_DIM; Kpad = KPAD_I; WB = WiB;
    }

    // ---- staging lane geometry (LDS[seg][c8] holds global
    //      (row = seg*2 + ((c8^(seg&7))>>2), kchunk = (c8^(seg&7))&3)) ----
    const int l8  = lane >> 3;                 // seg within group
    const int c8w = lane & 7;                  // LDS chunk this lane fills
    const int s8  = c8w ^ l8;                  // source-side swizzled chunk
    const int spr = s8 >> 2;                   // source row parity
    const int skc = (s8 & 3) * 8;              // source k-col (elements)

    const int asg0 = wid * 16 + l8;            // A op0 seg
    const float* aptr0 = X + (size_t)(mb * 128 + asg0 * 2 + spr) * XCOLS + xoff;
    const float* aptr1 = aptr0 + (size_t)16 * XCOLS;   // op1 seg = asg0 + 8

    float4 Sa[2], Sb[2];                       // single A reg set (static idx)

    auto ALOAD = [&](int tk) {
        int kc = tk * 32 + skc;
        if (xoff + kc + 8 > XCOLS) kc = XCOLS - xoff - 8;  // tail: junk x 0-B
        Sa[0] = *(const float4*)(aptr0 + kc);
        Sa[1] = *(const float4*)(aptr0 + kc + 4);
        Sb[0] = *(const float4*)(aptr1 + kc);
        Sb[1] = *(const float4*)(aptr1 + kc + 4);
    };
    auto AWRITE = [&](int slot) {              // consumes Sa/Sb (auto vm-wait)
        unsigned short* sA = sA3[slot];
        uint4 w0, w1;
        w0.x = (unsigned)f2bf(Sa[0].x) | ((unsigned)f2bf(Sa[0].y) << 16);
        w0.y = (unsigned)f2bf(Sa[0].z) | ((unsigned)f2bf(Sa[0].w) << 16);
        w0.z = (unsigned)f2bf(Sa[1].x) | ((unsigned)f2bf(Sa[1].y) << 16);
        w0.w = (unsigned)f2bf(Sa[1].z) | ((unsigned)f2bf(Sa[1].w) << 16);
        w1.x = (unsigned)f2bf(Sb[0].x) | ((unsigned)f2bf(Sb[0].y) << 16);
        w1.y = (unsigned)f2bf(Sb[0].z) | ((unsigned)f2bf(Sb[0].w) << 16);
        w1.z = (unsigned)f2bf(Sb[1].x) | ((unsigned)f2bf(Sb[1].y) << 16);
        w1.w = (unsigned)f2bf(Sb[1].z) | ((unsigned)f2bf(Sb[1].w) << 16);
        *(uint4*)(sA + asg0 * 64 + c8w * 8) = w0;
        *(uint4*)(sA + (asg0 + 8) * 64 + c8w * 8) = w1;
    };
    auto ISSUE_B = [&](int tk, int slot) {
        const int kb = tk * 32;
        unsigned short* sB = sB3[slot];
        #pragma unroll
        for (int j = 0; j < 2; ++j) {
            const int i  = wid * 2 + j;                // 0..7
            const int rt = (i * 8 + l8) * 2 + spr;     // tile row
            const unsigned short* s =
                WB + (size_t)(nb * 128 + rt) * Kpad + kb + skc;
            gload16(s, sB + i * 512);                  // linear 1KB dest
        }
    };

    // ---- fragment read geometry (0-conflict) ----
    const int fr  = lane & 15;
    const int g   = lane >> 4;
    const int lro = (fr >> 1) * 64 + ((((fr & 1) * 4) + g) ^ (fr >> 1)) * 8;
    const int aro = wm * 2048 + lro;           // + mi*512
    const int bro = wn * 2048 + lro;           // + ni*512

    f32x4 acc[4][4];
    #pragma unroll
    for (int i = 0; i < 4; ++i)
        #pragma unroll
        for (int j = 0; j < 4; ++j) acc[i][j] = (f32x4)0.0f;

    auto COMPUTE = [&](int slot) {
        const unsigned short* sA = sA3[slot];
        const unsigned short* sB = sB3[slot];
        bf16x8 af[4], bfr[4];
        #pragma unroll
        for (int mi = 0; mi < 4; ++mi)
            af[mi] = *(const bf16x8*)(sA + aro + mi * 512);
        #pragma unroll
        for (int ni = 0; ni < 4; ++ni)
            bfr[ni] = *(const bf16x8*)(sB + bro + ni * 512);
        __builtin_amdgcn_s_setprio(1);
        #pragma unroll
        for (int mi = 0; mi < 4; ++mi)
            #pragma unroll
            for (int ni = 0; ni < 4; ++ni)
                acc[mi][ni] = __builtin_amdgcn_mfma_f32_16x16x32_bf16(
                    af[mi], bfr[ni], acc[mi][ni], 0, 0, 0);
        __builtin_amdgcn_s_setprio(0);
    };

    // ---- prologue: tiles 0,1 in flight ----
    ALOAD(k0s + 0);                 // A(0)                     [4 vm]
    ISSUE_B(k0s + 0, 0);            // B(0) -> slot0            [2 vm]
    AWRITE(0);                      // A(0) -> slot0 (auto-waits A(0) loads)
    ALOAD(k0s + 1);                 // A(1)                     [4 vm]
    ISSUE_B(k0s + 1, 1);            // B(1) -> slot1            [2 vm]
    LGKM0;
    VMCNT(6);                       // B(0) landed; A(1)+B(1) in flight
    BARRIER();                      // tile 0 ready (slot0)

    // ---- main loop: ONE barrier per step.
    // step t: read slot t%3; A(t+1) -> slot (t+1)%3; B(t+2) -> slot (t+2)%3.
    int sl0 = 0, sl1 = 1, sl2 = 2;
    for (int t = 0; t < nt - 2; ++t) {
        AWRITE(sl1);                // A(t+1) -> ring (auto vmcnt(2): its loads)
        ALOAD(k0s + t + 2);         // A(t+2) -> regs
        ISSUE_B(k0s + t + 2, sl2);  // B(t+2) -> ring
        COMPUTE(sl0);               // tile t (overlaps in-flight DMA)
        LGKM0;                      // A writes + frag reads drained
        VMCNT(6);                   // B(t+1) landed; A(t+2)+B(t+2) in flight
        BARRIER();                  // publish tile t+1; skew <= 1 enforced
        const int tmp = sl0; sl0 = sl1; sl1 = sl2; sl2 = tmp;
    }
    // ---- tail: tiles nt-2, nt-1 ----
    AWRITE(sl1);                    // A(nt-1) -> ring (auto-retires its loads)
    COMPUTE(sl0);                   // tile nt-2
    LGKM0;
    VMCNT(0);                       // drain B(nt-1) DMA
    BARRIER();
    COMPUTE(sl1);                   // tile nt-1

    // ---- epilogue (r6-proven) ----
    const int cb = nb * 128 + wn * 64;
    const int rb = mb * 128 + wm * 64 + (lane >> 4) * 4;
    if (isUser) {
        #pragma unroll
        for (int ni = 0; ni < 4; ++ni) {
            const int col = cb + ni * 16 + fr;
            const float bv = bu[col];
            #pragma unroll
            for (int mi = 0; mi < 4; ++mi) {
                f32x4 v = acc[mi][ni];
                #pragma unroll
                for (int r = 0; r < 4; ++r) {
                    const int row = rb + mi * 16 + r;
                    Uemb[(size_t)row * LATENT + col] = f2bf(fmaxf(v[r] + bv, 0.0f));
                }
            }
        }
    } else {
        unsigned short* P = kh ? P1 : P0;
        #pragma unroll
        for (int ni = 0; ni < 4; ++ni) {
            const int col = cb + ni * 16 + fr;
            #pragma unroll
            for (int mi = 0; mi < 4; ++mi) {
                f32x4 v = acc[mi][ni];
                #pragma unroll
                for (int r = 0; r < 4; ++r) {
                    const int row = rb + mi * 16 + r;
                    P[(size_t)row * LATENT + col] = f2bf(v[r]);   // partial
                }
            }
        }
    }
}

// ---- Kernel 3: out[b] = sum_d U[b,d] * relu(P0[b,d] + P1[b,d] + bi[d]) ----
__global__ void rowdot(const unsigned short* __restrict__ U,
                       const unsigned short* __restrict__ P0,
                       const unsigned short* __restrict__ P1,
                       const float* __restrict__ bi,
                       float* __restrict__ out) {
    const int lane = threadIdx.x & 63;
    const int w    = threadIdx.x >> 6;
    const int row  = blockIdx.x * 4 + w;
    const size_t base = (size_t)row * LATENT + lane * 8;
    const uint4 uv = *(const uint4*)(U  + base);
    const uint4 p0 = *(const uint4*)(P0 + base);
    const uint4 p1 = *(const uint4*)(P1 + base);
    const float4 b0 = *(const float4*)(bi + lane * 8);
    const float4 b1 = *(const float4*)(bi + lane * 8 + 4);
    const float bb[8] = {b0.x, b0.y, b0.z, b0.w, b1.x, b1.y, b1.z, b1.w};
    const unsigned int* up = (const unsigned int*)&uv;
    const unsigned int* q0 = (const unsigned int*)&p0;
    const unsigned int* q1 = (const unsigned int*)&p1;
    float acc = 0.0f;
    #pragma unroll
    for (int q = 0; q < 4; ++q) {
        float ilo = fmaxf(bf2f(q0[q] & 0xffffu) + bf2f(q1[q] & 0xffffu) + bb[2 * q], 0.0f);
        float ihi = fmaxf(bf2f(q0[q] >> 16)     + bf2f(q1[q] >> 16)     + bb[2 * q + 1], 0.0f);
        acc += bf2f(up[q] & 0xffffu) * ilo;
        acc += bf2f(up[q] >> 16)     * ihi;
    }
    #pragma unroll
    for (int off = 32; off >= 1; off >>= 1)
        acc += __shfl_xor(acc, off, 64);
    if (lane == 0) out[row] = acc;
}

extern "C" void kernel_launch(void* const* d_in, const int* in_sizes, int n_in,
                              void* d_out, int out_size, void* d_ws, size_t ws_size,
                              hipStream_t stream) {
    const float* x  = (const float*)d_in[0];
    const float* Wu = (const float*)d_in[1];
    const float* bu = (const float*)d_in[2];
    const float* Wi = (const float*)d_in[3];
    const float* bi = (const float*)d_in[4];
    float* out = (float*)d_out;

    unsigned short* WuB  = (unsigned short*)d_ws;                 // 512*3712 bf16
    unsigned short* WiB  = WuB + (size_t)LATENT * KPAD_U;         // 512*6144 bf16
    unsigned short* Uemb = WiB + (size_t)LATENT * KPAD_I;         // 8192*512 bf16
    unsigned short* P0   = Uemb + (size_t)BATCH * LATENT;         // 8192*512 bf16
    unsigned short* P1   = P0   + (size_t)BATCH * LATENT;         // 8192*512 bf16

    convert_w<<<dim3((KPAD_U + 255) / 256, LATENT), 256, 0, stream>>>(Wu, WuB, USER_DIM, KPAD_U);
    convert_w<<<dim3((KPAD_I + 255) / 256, LATENT), 256, 0, stream>>>(Wi, WiB, ITEM_DIM, KPAD_I);

    // 768 blocks = 3 per CU co-resident; 1 user + 2 item halves per CU.
    gemm_fused<<<768, 256, 0, stream>>>(x, WuB, bu, WiB, Uemb, P0, P1);

    rowdot<<<BATCH / 4, 256, 0, stream>>>(Uemb, P0, P1, bi, out);
}